// Round 7
// baseline (1486.762 us; speedup 1.0000x reference)
//
#include <hip/hip_runtime.h>
#include <hip/hip_bf16.h>

#define NN 50000
#define NE 800000
#define DD 256
#define EPSV 1e-5f

typedef float f32x4 __attribute__((ext_vector_type(4)));
typedef short bf16x8s __attribute__((ext_vector_type(8)));
typedef unsigned int uint32;
typedef uint32 u32x4 __attribute__((ext_vector_type(4)));

__device__ __forceinline__ float bf2f(unsigned int u16v) {
  return __builtin_bit_cast(float, u16v << 16);
}
__device__ __forceinline__ unsigned short f2bf(float f) {
  return __builtin_bit_cast(unsigned short, __float2bfloat16(f));
}
__device__ __forceinline__ void mfma_bf16(bf16x8s a, bf16x8s b, f32x4& c) {
  asm("v_mfma_f32_16x16x32_bf16 %0, %1, %2, %0" : "+v"(c) : "v"(a), "v"(b));
}
__device__ __forceinline__ void gload_lds16(const void* g, void* l) {
  __builtin_amdgcn_global_load_lds((const __attribute__((address_space(1))) void*)g,
                                   (__attribute__((address_space(3))) void*)l, 16, 0, 0);
}

// fp32 chunked activation layout: chunk c (16 feats), node n:
//   float base = (c*NN + n)*16 ; 16 f32 = 64 B per node-chunk.

// ---------------- CSR build (by dst) ----------------

__global__ void deg_count_k(const int* __restrict__ ei, int* __restrict__ deg) {
  int e = blockIdx.x * 256 + threadIdx.x;
  if (e < NE) atomicAdd(&deg[ei[NE + e]], 1);
}

__global__ void scan1_k(const int* __restrict__ deg, int* __restrict__ row_ptr,
                        int* __restrict__ blockSums) {
  __shared__ int s[1024];
  int gid = blockIdx.x * 1024 + threadIdx.x;
  int v = (gid < NN) ? deg[gid] : 0;
  s[threadIdx.x] = v;
  __syncthreads();
  for (int off = 1; off < 1024; off <<= 1) {
    int t = (threadIdx.x >= off) ? s[threadIdx.x - off] : 0;
    __syncthreads();
    s[threadIdx.x] += t;
    __syncthreads();
  }
  if (gid < NN) row_ptr[gid] = s[threadIdx.x] - v;
  if (threadIdx.x == 1023) blockSums[blockIdx.x] = s[1023];
}

__global__ void scan2_k(const int* __restrict__ blockSums, int* __restrict__ blockOffs,
                        int* __restrict__ row_ptr, int nblocks) {
  if (threadIdx.x == 0) {
    int run = 0;
    for (int i = 0; i < nblocks; ++i) { blockOffs[i] = run; run += blockSums[i]; }
    row_ptr[NN] = run;
  }
}

// scan3 + degree histogram (64 capped bins) fused
__global__ void scan3_k(int* __restrict__ row_ptr, const int* __restrict__ blockOffs,
                        const int* __restrict__ deg, float* __restrict__ deg_inv,
                        int* __restrict__ cursor, int* __restrict__ dh) {
  int gid = blockIdx.x * 1024 + threadIdx.x;
  if (gid < NN) {
    int v = row_ptr[gid] + blockOffs[blockIdx.x];
    row_ptr[gid] = v;
    cursor[gid] = v;
    int d = deg[gid];
    deg_inv[gid] = 1.0f / (float)max(d, 1);
    atomicAdd(&dh[min(d, 63)], 1);
  }
}

__global__ void dscan_k(const int* __restrict__ dh, int* __restrict__ dcur) {
  if (threadIdx.x == 0) {
    int run = 0;
    for (int i = 0; i < 64; ++i) { dcur[i] = run; run += dh[i]; }
  }
}

__global__ void dperm_k(const int* __restrict__ deg, int* __restrict__ dcur,
                        int* __restrict__ nperm) {
  int gid = blockIdx.x * 256 + threadIdx.x;
  if (gid < NN) {
    int pos = atomicAdd(&dcur[min(deg[gid], 63)], 1);
    nperm[pos] = gid;
  }
}

__global__ void csr_fill_k(const int* __restrict__ ei, int* __restrict__ cursor,
                           unsigned short* __restrict__ col16) {
  int e = blockIdx.x * 256 + threadIdx.x;
  if (e < NE) {
    int pos = atomicAdd(&cursor[ei[NE + e]], 1);
    col16[pos] = (unsigned short)ei[e];
  }
}

// ---------------- prep: x relayout (fp32 chunked) + W^T hi/lo bf16 planes ----------------

__global__ __launch_bounds__(256) void prep_k(
    const float* __restrict__ x,
    const float* __restrict__ W0, const float* __restrict__ W1,
    const float* __restrict__ W2, const float* __restrict__ W3,
    const float* __restrict__ W4, const float* __restrict__ W5,
    float* __restrict__ xF, unsigned short* __restrict__ wt) {
  if (blockIdx.x < 3125) {
    int unit = blockIdx.x * 256 + threadIdx.x;
    int c = unit / NN, node = unit - c * NN;
    const float4* src = reinterpret_cast<const float4*>(x + (size_t)node * DD + c * 16);
    float4* dst = reinterpret_cast<float4*>(xF + (size_t)unit * 16);
#pragma unroll
    for (int i = 0; i < 4; ++i) dst[i] = src[i];
  } else {
    int bb = blockIdx.x - 3125;
    int p = bb >> 6;
    const float* W = (p == 0) ? W0 : (p == 1) ? W1 : (p == 2) ? W2
                     : (p == 3) ? W3 : (p == 4) ? W4 : W5;
    unsigned short* thi = wt + (size_t)(2 * p) * 65536;
    unsigned short* tlo = wt + (size_t)(2 * p + 1) * 65536;
    int gid = (bb & 63) * 256 + threadIdx.x;
    int n = gid >> 6, k4 = (gid & 63) << 2;
    ushort4 hi, lo;
    unsigned short* hp = &hi.x; unsigned short* lp = &lo.x;
#pragma unroll
    for (int r = 0; r < 4; ++r) {
      float v = W[(size_t)(k4 + r) * DD + n];
      unsigned short h = f2bf(v);
      hp[r] = h;
      lp[r] = f2bf(v - bf2f(h));
    }
    *reinterpret_cast<ushort4*>(thi + (size_t)n * DD + k4) = hi;
    *reinterpret_cast<ushort4*>(tlo + (size_t)n * DD + k4) = lo;
  }
}

// ---------------- aggregation: degree-sorted, fp32, 4 lanes/node, 4-deep unroll ----------------
// Grid 12512 = 2 phases x 8 chunks x 782 groups; chunk&7 == b%8 -> one XCD per chunk table.

__global__ __launch_bounds__(256) void sage_agg_k(
    const float* __restrict__ act, const int* __restrict__ rp,
    const unsigned short* __restrict__ ci, const float* __restrict__ deg_inv,
    const int* __restrict__ nperm, float* __restrict__ agg) {
  int b = blockIdx.x;
  int ph = (b >= 6256);
  int bb = ph ? b - 6256 : b;
  int c = ph * 8 + (bb & 7);
  int slot = (bb >> 3) * 64 + (threadIdx.x >> 2);
  if (slot >= NN) return;
  int node = nperm[slot];                  // degree-sorted -> uniform degree per wave
  int q4 = (threadIdx.x & 3) * 4;

  const float* base = act + (size_t)c * NN * 16;
  int beg = rp[node], end = rp[node + 1];

  f32x4 a0 = (f32x4)0.f, a1 = (f32x4)0.f, a2 = (f32x4)0.f, a3 = (f32x4)0.f;
  int e = beg;
  for (; e + 4 <= end; e += 4) {
    int s0 = (int)ci[e], s1 = (int)ci[e + 1], s2 = (int)ci[e + 2], s3 = (int)ci[e + 3];
    a0 += *reinterpret_cast<const f32x4*>(base + (size_t)s0 * 16 + q4);
    a1 += *reinterpret_cast<const f32x4*>(base + (size_t)s1 * 16 + q4);
    a2 += *reinterpret_cast<const f32x4*>(base + (size_t)s2 * 16 + q4);
    a3 += *reinterpret_cast<const f32x4*>(base + (size_t)s3 * 16 + q4);
  }
  for (; e < end; ++e)
    a0 += *reinterpret_cast<const f32x4*>(base + (size_t)ci[e] * 16 + q4);
  a0 = (a0 + a1) + (a2 + a3);
  float di = deg_inv[node];
  a0 *= di;
  *reinterpret_cast<f32x4*>(agg + ((size_t)c * NN + node) * 16 + q4) = a0;
}

// ---------------- MFMA GEMM: 64x256 tile, BK=32, 8 waves, double-buffered 2-phase ----------------
// {STAGE(next); COMPUTE(cur); __syncthreads()} -- stage latency hides under MFMA.
// LDS 2 x 40KB -> 2 blocks/CU (16 waves/CU).

template <bool DO_BN>
__global__ __launch_bounds__(512) void sage_gemm_k(
    const float* __restrict__ aggF, const float* __restrict__ hF,
    const unsigned short* __restrict__ wlHi, const unsigned short* __restrict__ wlLo,
    const unsigned short* __restrict__ wrHi, const unsigned short* __restrict__ wrLo,
    const float* __restrict__ bias,
    const float* __restrict__ gamma, const float* __restrict__ beta,
    const float* __restrict__ mean, const float* __restrict__ var,
    float* __restrict__ outF, float* __restrict__ outC) {
  __shared__ __attribute__((aligned(128))) char lds[2][40960];  // per buf: A 8KB | B 32KB

  int tid = threadIdx.x, wave = tid >> 6, l = tid & 63;
  int lr = l & 15, lq = l >> 4;
  int sub = wave & 3, h = wave >> 2;
  int m0 = blockIdx.x * 64;

  f32x4 acc[8];
#pragma unroll
  for (int j = 0; j < 8; ++j) acc[j] = (f32x4)0.f;

  auto STAGE = [&](char* L, int t) {
    bool first = t < 8;
    const float* Ap = first ? aggF : hF;
    int t7 = t & 7;
#pragma unroll
    for (int i = 0; i < 5; ++i) {
      int u = wave * 5 + i;
      if (u < 8) {
        int row = m0 + (u & 3) * 16 + lr;
        row = row < NN ? row : NN - 1;
        gload_lds16(Ap + ((size_t)(2 * t7 + (u >> 2)) * NN + row) * 16 + lq * 4,
                    L + u * 1024 + l * 16);
      } else {
        int ub = u - 8, j = ub >> 1, p = ub & 1;
        const unsigned short* W = first ? (p ? wlLo : wlHi) : (p ? wrLo : wrHi);
        gload_lds16(W + (size_t)(j * 16 + lr) * DD + t7 * 32 + lq * 8,
                    L + 8192 + ub * 1024 + l * 16);
      }
    }
  };

  auto COMPUTE = [&](const char* L) {
    // A fragment: 8 f32 -> truncation hi/lo bf16 split (bit-identical to R6)
    int ua = (lq >> 1) * 4 + sub;
    int abase = ua * 1024 + (lq & 1) * 512 + lr * 16;
    f32x4 f0 = *reinterpret_cast<const f32x4*>(&L[abase]);
    f32x4 f1 = *reinterpret_cast<const f32x4*>(&L[abase + 256]);
    float af[8] = {f0[0], f0[1], f0[2], f0[3], f1[0], f1[1], f1[2], f1[3]};
    u32x4 hw, lw;
#pragma unroll
    for (int i = 0; i < 4; ++i) {
      uint32 b0 = __builtin_bit_cast(uint32, af[2 * i]);
      uint32 b1 = __builtin_bit_cast(uint32, af[2 * i + 1]);
      hw[i] = (b1 & 0xffff0000u) | (b0 >> 16);
      float l0 = af[2 * i] - __builtin_bit_cast(float, b0 & 0xffff0000u);
      float l1 = af[2 * i + 1] - __builtin_bit_cast(float, b1 & 0xffff0000u);
      lw[i] = (uint32)f2bf(l0) | ((uint32)f2bf(l1) << 16);
    }
    bf16x8s aH = __builtin_bit_cast(bf16x8s, hw);
    bf16x8s aL = __builtin_bit_cast(bf16x8s, lw);
#pragma unroll
    for (int jj = 0; jj < 8; ++jj) {
      int j = h * 8 + jj;
      bf16x8s bH = *reinterpret_cast<const bf16x8s*>(&L[8192 + (j * 2 + 0) * 1024 + l * 16]);
      bf16x8s bL = *reinterpret_cast<const bf16x8s*>(&L[8192 + (j * 2 + 1) * 1024 + l * 16]);
      mfma_bf16(aH, bH, acc[jj]);
      mfma_bf16(aH, bL, acc[jj]);
      mfma_bf16(aL, bH, acc[jj]);
    }
  };

  STAGE(lds[0], 0);
  __syncthreads();
#pragma unroll 1
  for (int t = 0; t < 16; ++t) {
    if (t < 15) STAGE(lds[(t + 1) & 1], t + 1);  // loads in flight under compute
    COMPUTE(lds[t & 1]);
    __syncthreads();  // drains next-buf loads AFTER compute; protects buf reuse
  }

  // ---- epilogue (identical to R6) ----
#pragma unroll
  for (int jj = 0; jj < 8; ++jj) {
    int cj = h * 8 + jj;
    int n = cj * 16 + lr;
    float bb = bias[n], sc = 0.f, sh = 0.f;
    if (DO_BN) {
      float s = gamma[n] * rsqrtf(var[n] + EPSV);
      sc = s;
      sh = beta[n] - mean[n] * s;
    }
#pragma unroll
    for (int reg = 0; reg < 4; ++reg) {
      int m = m0 + sub * 16 + lq * 4 + reg;
      if (m < NN) {
        float v = acc[jj][reg] + bb;
        if (DO_BN) {
          size_t ui = ((size_t)cj * NN + m) * 16 + lr;
          v = fmaxf(v * sc + sh, 0.f) + hF[ui];
          outC[ui] = v;
        } else {
          outF[(size_t)m * DD + n] = v;
        }
      }
    }
  }
}

// ---------------- launch ----------------

extern "C" void kernel_launch(void* const* d_in, const int* in_sizes, int n_in,
                              void* d_out, int out_size, void* d_ws, size_t ws_size,
                              hipStream_t stream) {
  const float* x   = (const float*)d_in[0];
  const int*   ei  = (const int*)d_in[1];
  const float* Wl[3] = {(const float*)d_in[2], (const float*)d_in[5], (const float*)d_in[8]};
  const float* Wr[3] = {(const float*)d_in[3], (const float*)d_in[6], (const float*)d_in[9]};
  const float* bs[3] = {(const float*)d_in[4], (const float*)d_in[7], (const float*)d_in[10]};
  const float* g0  = (const float*)d_in[11];
  const float* be0 = (const float*)d_in[12];
  const float* mu0 = (const float*)d_in[13];
  const float* va0 = (const float*)d_in[14];
  const float* g1  = (const float*)d_in[15];
  const float* be1 = (const float*)d_in[16];
  const float* mu1 = (const float*)d_in[17];
  const float* va1 = (const float*)d_in[18];
  float* out = (float*)d_out;

  char* w = (char*)d_ws;
  const size_t o_deg    = 0;            // NN ints
  const size_t o_dh     = 204800;       // 64 ints
  const size_t o_dcur   = 205056;       // 64 ints
  const size_t o_rowptr = 262144;
  const size_t o_cursor = 524288;
  const size_t o_col16  = 786432;       // NE u16 = 1.6 MB
  const size_t o_deginv = 2621440;
  const size_t o_bsum   = 2883584;
  const size_t o_boff   = 2887680;
  const size_t o_nperm  = 2891776;      // NN ints
  const size_t o_wt     = 3145728;      // 12 planes * 131072 B
  const size_t ACT      = (size_t)16 * NN * 64;  // 51.2 MB
  const size_t o_xF     = 6291456;
  const size_t o_h1F    = o_xF + ACT;
  const size_t o_aggF   = o_xF + 2 * ACT;        // end ~159.9 MB

  int*   deg     = (int*)(w + o_deg);
  int*   dh      = (int*)(w + o_dh);
  int*   dcur    = (int*)(w + o_dcur);
  int*   row_ptr = (int*)(w + o_rowptr);
  int*   cursor  = (int*)(w + o_cursor);
  unsigned short* col16 = (unsigned short*)(w + o_col16);
  float* deg_inv = (float*)(w + o_deginv);
  int*   bsum    = (int*)(w + o_bsum);
  int*   boff    = (int*)(w + o_boff);
  int*   nperm   = (int*)(w + o_nperm);
  unsigned short* wt = (unsigned short*)(w + o_wt);
  float* xF   = (float*)(w + o_xF);
  float* h1F  = (float*)(w + o_h1F);
  float* aggF = (float*)(w + o_aggF);

  unsigned short* wlT[3][2];
  unsigned short* wrT[3][2];
  for (int l = 0; l < 3; ++l) {
    wlT[l][0] = wt + (size_t)(4 * l + 0) * 65536;
    wlT[l][1] = wt + (size_t)(4 * l + 1) * 65536;
    wrT[l][0] = wt + (size_t)(4 * l + 2) * 65536;
    wrT[l][1] = wt + (size_t)(4 * l + 3) * 65536;
  }

  const int SCAN_BLOCKS = (NN + 1023) / 1024;  // 49

  // ---- CSR build + degree sort ----
  hipMemsetAsync(w, 0, 205312, stream);  // deg + dh
  deg_count_k<<<NE / 256, 256, 0, stream>>>(ei, deg);
  scan1_k<<<SCAN_BLOCKS, 1024, 0, stream>>>(deg, row_ptr, bsum);
  scan2_k<<<1, 64, 0, stream>>>(bsum, boff, row_ptr, SCAN_BLOCKS);
  scan3_k<<<SCAN_BLOCKS, 1024, 0, stream>>>(row_ptr, boff, deg, deg_inv, cursor, dh);
  dscan_k<<<1, 64, 0, stream>>>(dh, dcur);
  dperm_k<<<(NN + 255) / 256, 256, 0, stream>>>(deg, dcur, nperm);
  csr_fill_k<<<NE / 256, 256, 0, stream>>>(ei, cursor, col16);

  // ---- prep: x relayout + weight planes ----
  prep_k<<<3509, 256, 0, stream>>>(x, Wl[0], Wr[0], Wl[1], Wr[1], Wl[2], Wr[2], xF, wt);

  const int AGRID = 12512;           // 2 phases x 8 chunks x 782 groups
  dim3 ggrid((NN + 63) / 64);        // 782

  // ---- layer 0: x -> h1 ----
  sage_agg_k<<<AGRID, 256, 0, stream>>>(xF, row_ptr, col16, deg_inv, nperm, aggF);
  sage_gemm_k<true><<<ggrid, 512, 0, stream>>>(
      aggF, xF, wlT[0][0], wlT[0][1], wrT[0][0], wrT[0][1],
      bs[0], g0, be0, mu0, va0, nullptr, h1F);
  // ---- layer 1: h1 -> h2 (into xF) ----
  sage_agg_k<<<AGRID, 256, 0, stream>>>(h1F, row_ptr, col16, deg_inv, nperm, aggF);
  sage_gemm_k<true><<<ggrid, 512, 0, stream>>>(
      aggF, h1F, wlT[1][0], wlT[1][1], wrT[1][0], wrT[1][1],
      bs[1], g1, be1, mu1, va1, nullptr, xF);
  // ---- layer 2: h2 -> out (fp32 row-major) ----
  sage_agg_k<<<AGRID, 256, 0, stream>>>(xF, row_ptr, col16, deg_inv, nperm, aggF);
  sage_gemm_k<false><<<ggrid, 512, 0, stream>>>(
      aggF, xF, wlT[2][0], wlT[2][1], wrT[2][0], wrT[2][1],
      bs[2], nullptr, nullptr, nullptr, nullptr, out, nullptr);
}